// Round 3
// baseline (312.169 us; speedup 1.0000x reference)
//
#include <hip/hip_runtime.h>
#include <hip/hip_bf16.h>
#include <stdint.h>

using bf16 = __hip_bfloat16;

typedef __attribute__((ext_vector_type(8))) short short8;
typedef __attribute__((ext_vector_type(4))) float float4v;

namespace {
constexpr int kL  = 4096;
constexpr int kD  = 384;
constexpr int kGW = 64;
constexpr int kM  = 32768;
constexpr int kAP = 392;   // padded agg LDS stride (bf16): 784 B/row -> 2-way (free) banks

constexpr size_t nValue = (size_t)kM * kD;
constexpr size_t nW     = (size_t)kD * kD;
constexpr size_t nWcat  = (size_t)96 * kD;   // 96x384 (transposed cat weight)

// workspace offsets (bytes)
constexpr size_t oWvt  = 0;                                    // bf16 Wv^T [384][384]
constexpr size_t oWot  = oWvt  + nW * 2;                       // bf16 Wo^T [384][384]
constexpr size_t oWch  = oWot  + nW * 2;                       // bf16 Wcat^T hi [96][384]
constexpr size_t oWcl  = oWch  + nWcat * 2;                    // bf16 Wcat^T lo [96][384]
constexpr size_t oBcat = oWcl  + nWcat * 2;                    // f32 [96]
constexpr size_t oVB   = (oBcat + 96 * 4 + 255) & ~size_t(255);// bf16 v [kM][384]
constexpr size_t oProj = oVB   + nValue * 2;                   // f32 [kM][96]
}

__device__ __forceinline__ short bf16bits(float f) {
  bf16 h = __float2bfloat16(f);
  return *reinterpret_cast<short*>(&h);
}

__device__ __forceinline__ float bf16raw2f(unsigned short u) {
  union { unsigned int i; float f; } c;
  c.i = ((unsigned int)u) << 16;
  return c.f;
}

__device__ __forceinline__ short8 pack_hi8(const float4& f0, const float4& f1) {
  short8 hx;
  hx[0] = bf16bits(f0.x); hx[1] = bf16bits(f0.y);
  hx[2] = bf16bits(f0.z); hx[3] = bf16bits(f0.w);
  hx[4] = bf16bits(f1.x); hx[5] = bf16bits(f1.y);
  hx[6] = bf16bits(f1.z); hx[7] = bf16bits(f1.w);
  return hx;
}

__device__ __forceinline__ void pack_hilo8(const float4& f0, const float4& f1,
                                           short8& hx, short8& lx) {
  const float fv[8] = {f0.x, f0.y, f0.z, f0.w, f1.x, f1.y, f1.z, f1.w};
  #pragma unroll
  for (int q = 0; q < 8; ++q) {
    const bf16 h = __float2bfloat16(fv[q]);
    hx[q] = *reinterpret_cast<const short*>(&h);
    const bf16 lo = __float2bfloat16(fv[q] - __bfloat162float(h));
    lx[q] = *reinterpret_cast<const short*>(&lo);
  }
}

// -------------------------------------------------------------------------
// prep (weights only): Wv^T, Wo^T as bf16; Wcat^T split into hi/lo bf16 so
// the proj GEMM can run on MFMA with f32-level accuracy (err ~2^-17 rel).
// -------------------------------------------------------------------------
__global__ void prep_kernel(const float* __restrict__ Wv,
                            const float* __restrict__ Wo,
                            const float* __restrict__ Woff,
                            const float* __restrict__ Wwt,
                            const float* __restrict__ boff,
                            const float* __restrict__ bwt,
                            bf16* __restrict__ Wvt, bf16* __restrict__ Wot,
                            bf16* __restrict__ Wch, bf16* __restrict__ Wcl,
                            float* __restrict__ bcat)
{
  size_t i = (size_t)blockIdx.x * 256 + threadIdx.x;
  if (i < nW) {
    const int n = (int)(i / kD), k = (int)(i % kD);
    Wvt[i] = __float2bfloat16(Wv[(size_t)k * kD + n]);
    return;
  }
  i -= nW;
  if (i < nW) {
    const int n = (int)(i / kD), k = (int)(i % kD);
    Wot[i] = __float2bfloat16(Wo[(size_t)k * kD + n]);
    return;
  }
  i -= nW;
  if (i < nWcat) {
    const int n = (int)(i / kD), k = (int)(i % kD);
    const float val = (n < 64) ? Woff[(size_t)k * 64 + n] : Wwt[(size_t)k * 32 + (n - 64)];
    const bf16 h = __float2bfloat16(val);
    Wch[i] = h;
    Wcl[i] = __float2bfloat16(val - __bfloat162float(h));  // exact residual, then rounded
    return;
  }
  i -= nWcat;
  if (i < 96) bcat[i] = (i < 64) ? boff[i] : bwt[i - 64];
}

// -------------------------------------------------------------------------
// v GEMM body, LDS-free: vB[M,384] = value @ Wv + bv, bf16 out.
// 128x128 tile, 4 waves. Each wave owns a private 64x64 sub-tile:
//  A: f32 direct global->reg (16 rows x 128 B per frag, fully coalesced),
//     cast to bf16 in-register.
//  B: bf16 frags direct from L2 (Wv^T is 288 KB, L2-hot; one dwordx4/lane
//     covers 16 rows x 64 B = 16 full lines, zero waste).
// No __shared__, no __syncthreads -> waves pipeline independently; the
// barrier-lockstep vmcnt(0) drain (the measured ~3x-off-HBM-floor stall
// of rounds 0-2) is gone.
// -------------------------------------------------------------------------
__device__ __forceinline__
void vgemm_body(int bid, const float* __restrict__ A, const bf16* __restrict__ Bt,
                const float* __restrict__ bias, bf16* __restrict__ Cout)
{
  const int tid  = threadIdx.x;
  const int lane = tid & 63;
  const int wave = tid >> 6;
  const int bm = bid / 3, bn = bid % 3;   // 3 consecutive blocks share A rows (L2/L3)
  const int m0 = bm * 128, n0 = bn * 128;
  const int wm = (wave >> 1) * 64, wn = (wave & 1) * 64;
  const int r16 = lane & 15, quad = lane >> 4;

  float4v acc[4][4];
  #pragma unroll
  for (int i = 0; i < 4; ++i)
    #pragma unroll
    for (int j = 0; j < 4; ++j) acc[i][j] = (float4v){0.f, 0.f, 0.f, 0.f};

  const float* Abase = A  + (size_t)(m0 + wm + r16) * kD + quad * 8;
  const bf16*  Bbase = Bt + (size_t)(n0 + wn + r16) * kD + quad * 8;

  #pragma unroll
  for (int kt = 0; kt < 12; ++kt) {
    const int k0 = kt * 32;
    short8 av[4], bv[4];
    #pragma unroll
    for (int i = 0; i < 4; ++i) {
      const float* pa = Abase + (size_t)(i * 16) * kD + k0;
      av[i] = pack_hi8(*(const float4*)pa, *(const float4*)(pa + 4));
    }
    #pragma unroll
    for (int j = 0; j < 4; ++j)
      bv[j] = *(const short8*)(Bbase + (size_t)(j * 16) * kD + k0);
    #pragma unroll
    for (int i = 0; i < 4; ++i)
      #pragma unroll
      for (int j = 0; j < 4; ++j)
        acc[i][j] = __builtin_amdgcn_mfma_f32_16x16x32_bf16(av[i], bv[j], acc[i][j], 0, 0, 0);
  }

  #pragma unroll
  for (int j = 0; j < 4; ++j) {
    const int col = n0 + wn + j * 16 + r16;
    const float bj = bias[col];
    #pragma unroll
    for (int i = 0; i < 4; ++i) {
      const int mbase = m0 + wm + i * 16 + quad * 4;
      #pragma unroll
      for (int r = 0; r < 4; ++r)
        Cout[(size_t)(mbase + r) * kD + col] = __float2bfloat16(acc[i][j][r] + bj);
    }
  }
}

// -------------------------------------------------------------------------
// proj GEMM body, LDS-free split-bf16 MFMA: proj[M,96] = Q @ Wcat + bcat.
// acc = Ahi*Bhi + Ahi*Blo + Alo*Bhi (f32-level accuracy). Same no-barrier
// streaming structure as vgemm; B hi/lo (2x144 KB) is L2-hot.
// -------------------------------------------------------------------------
__device__ __forceinline__
void proj_body(int bid, const float* __restrict__ Q,
               const bf16* __restrict__ WhT, const bf16* __restrict__ WlT,
               const float* __restrict__ bc, float* __restrict__ proj)
{
  const int tid  = threadIdx.x;
  const int lane = tid & 63;
  const int wave = tid >> 6;
  const int m0 = bid * 128;
  const int wm = (wave >> 1) * 64, wn = (wave & 1) * 48;
  const int r16 = lane & 15, quad = lane >> 4;

  float4v acc[4][3];
  #pragma unroll
  for (int i = 0; i < 4; ++i)
    #pragma unroll
    for (int j = 0; j < 3; ++j) acc[i][j] = (float4v){0.f, 0.f, 0.f, 0.f};

  const float* Abase  = Q   + (size_t)(m0 + wm + r16) * kD + quad * 8;
  const bf16*  Bhbase = WhT + (size_t)(wn + r16) * kD + quad * 8;
  const bf16*  Blbase = WlT + (size_t)(wn + r16) * kD + quad * 8;

  #pragma unroll
  for (int kt = 0; kt < 12; ++kt) {
    const int k0 = kt * 32;
    short8 avh[4], avl[4];
    #pragma unroll
    for (int i = 0; i < 4; ++i) {
      const float* pa = Abase + (size_t)(i * 16) * kD + k0;
      pack_hilo8(*(const float4*)pa, *(const float4*)(pa + 4), avh[i], avl[i]);
    }
    #pragma unroll
    for (int j = 0; j < 3; ++j) {
      const short8 bvh = *(const short8*)(Bhbase + (size_t)(j * 16) * kD + k0);
      const short8 bvl = *(const short8*)(Blbase + (size_t)(j * 16) * kD + k0);
      #pragma unroll
      for (int i = 0; i < 4; ++i) {
        acc[i][j] = __builtin_amdgcn_mfma_f32_16x16x32_bf16(avh[i], bvh, acc[i][j], 0, 0, 0);
        acc[i][j] = __builtin_amdgcn_mfma_f32_16x16x32_bf16(avh[i], bvl, acc[i][j], 0, 0, 0);
        acc[i][j] = __builtin_amdgcn_mfma_f32_16x16x32_bf16(avl[i], bvh, acc[i][j], 0, 0, 0);
      }
    }
  }

  #pragma unroll
  for (int j = 0; j < 3; ++j) {
    const int col = wn + j * 16 + r16;
    const float bj = bc[col];
    #pragma unroll
    for (int i = 0; i < 4; ++i) {
      const int mbase = m0 + wm + i * 16 + quad * 4;
      #pragma unroll
      for (int r = 0; r < 4; ++r)
        proj[(size_t)(mbase + r) * 96 + col] = acc[i][j][r] + bj;
    }
  }
}

// -------------------------------------------------------------------------
// Fat kernel: blocks [0,256) proj GEMM, [256,1024) v GEMM. Zero LDS,
// zero barriers -> occupancy is VGPR-bound only; independent waves
// stream loads with compiler-counted vmcnt.
// -------------------------------------------------------------------------
__global__ __launch_bounds__(256)
void fat_kernel(const float* __restrict__ value, const bf16* __restrict__ Wvt,
                const float* __restrict__ bv,    bf16* __restrict__ vB,
                const float* __restrict__ Q,     const bf16* __restrict__ Wch,
                const bf16* __restrict__ Wcl,    const float* __restrict__ bcat,
                float* __restrict__ proj)
{
  const int pb = blockIdx.x;
  if (pb < 256) {
    proj_body(pb, Q, Wch, Wcl, bcat, proj);
  } else {
    vgemm_body(pb - 256, value, Wvt, bv, vB);
  }
}

// -------------------------------------------------------------------------
// tail kernel: fused sample + output GEMM. 512 blocks x 512 thr,
// 64 tokens/block, LDS 66,560 B -> 2 blocks/CU (vs 1 in round 2).
//  phase 1 (4 chunks of 16 tokens): coords+softmax -> scratch,
//    bilinear gather (softmax wt premultiplied) -> sAgg[64][392] bf16.
//  phase 2: out[64][384] = sAgg @ Wo^T + bo. A from LDS (2-way free
//    banks), B frags DIRECT from L2 (Wo^T 288 KB hot; each wave owns a
//    distinct 48-col slice -> zero redundancy) -> no barriers at all.
// XCD swizzle: chunk = (raw%8)*64 + raw/8 -> each XCD owns exactly one
// batch's v slice (3.1 MB, L2-resident).
// -------------------------------------------------------------------------
__global__ __launch_bounds__(512)
void tail_kernel(const float* __restrict__ proj, const bf16* __restrict__ v,
                 const bf16* __restrict__ Wot, const float* __restrict__ bo,
                 float* __restrict__ out)
{
  __shared__ __align__(16) char smem[66560];
  bf16*   sAgg  = (bf16*)smem;                 // [64][392] = 50176 B
  int4*   scoff = (int4*)(smem + 50176);       // [512] = 8192 B
  float4* scw   = (float4*)(smem + 58368);     // [512] = 8192 B

  const int raw   = blockIdx.x;
  const int chunk = (raw & 7) * 64 + (raw >> 3);
  const int m0    = chunk * 64;
  const int b     = m0 >> 12;
  const int l0    = m0 & 4095;
  const int t     = threadIdx.x;

  // ---------------- phase 1: sample ----------------
  for (int ct = 0; ct < 4; ++ct) {
    const int tok0 = ct * 16;
    {
      const int tl = t >> 5, pt = t & 31;      // 16 tok x 32 pts, 1/thread
      const int tok = tok0 + tl;
      const int l   = l0 + tok;
      const float* pb_ = proj + (size_t)(m0 + tok) * 96;
      const float2 off = *(const float2*)(pb_ + 2 * pt);
      const int h = pt >> 2, p = pt & 3;
      const float4 lg = *(const float4*)(pb_ + 64 + h * 4);
      const float g[4] = {lg.x, lg.y, lg.z, lg.w};
      const float mx = fmaxf(fmaxf(g[0], g[1]), fmaxf(g[2], g[3]));
      float e[4], sum = 0.f;
      #pragma unroll
      for (int jj = 0; jj < 4; ++jj) { e[jj] = expf(g[jj] - mx); sum += e[jj]; }
      const float wt = e[p] / sum;
      const float refx = (float)(l & 63) * (1.0f / 63.0f);
      const float refy = (float)(l >> 6) * (1.0f / 63.0f);
      const float locx = fminf(fmaxf(refx + off.x, 0.f), 1.f);
      const float locy = fminf(fmaxf(refy + off.y, 0.f), 1.f);
      const float ph = locx * 63.0f;           // faithful: component 0 -> row coord
      const float pw = locy * 63.0f;
      const float fy = floorf(ph), fx = floorf(pw);
      const int y0 = (int)fy, x0 = (int)fx;
      const int y1 = min(y0 + 1, 63), x1 = min(x0 + 1, 63);
      const float wy = ph - fy, wx = pw - fx;
      scoff[tl * 32 + pt] = make_int4((y0 * kGW + x0) * kD, (y0 * kGW + x1) * kD,
                                      (y1 * kGW + x0) * kD, (y1 * kGW + x1) * kD);
      scw[tl * 32 + pt] = make_float4(wt * (1.f - wy) * (1.f - wx), wt * (1.f - wy) * wx,
                                      wt * wy * (1.f - wx),         wt * wy * wx);
    }
    __syncthreads();
    #pragma unroll
    for (int it = 0; it < 3; ++it) {
      const int task = t + it * 512;           // 0..1535 = 16 tok x 96
      const int tl = task / 96;
      const int q  = task - tl * 96;
      const int h  = q / 12;
      const int col = q * 4;                   // = h*48 + (q%12)*4
      const unsigned short* vb = (const unsigned short*)(v + (size_t)b * kL * kD + col);
      float4v acc = (float4v){0.f, 0.f, 0.f, 0.f};
      #pragma unroll
      for (int p = 0; p < 4; ++p) {
        const int4   o = scoff[tl * 32 + h * 4 + p];
        const float4 w = scw  [tl * 32 + h * 4 + p];
        const ushort4 u0 = *(const ushort4*)(vb + o.x);
        const ushort4 u1 = *(const ushort4*)(vb + o.y);
        const ushort4 u2 = *(const ushort4*)(vb + o.z);
        const ushort4 u3 = *(const ushort4*)(vb + o.w);
        acc[0] += w.x * bf16raw2f(u0.x) + w.y * bf16raw2f(u1.x)
                + w.z * bf16raw2f(u2.x) + w.w * bf16raw2f(u3.x);
        acc[1] += w.x * bf16raw2f(u0.y) + w.y * bf16raw2f(u1.y)
                + w.z * bf16raw2f(u2.y) + w.w * bf16raw2f(u3.y);
        acc[2] += w.x * bf16raw2f(u0.z) + w.y * bf16raw2f(u1.z)
                + w.z * bf16raw2f(u2.z) + w.w * bf16raw2f(u3.z);
        acc[3] += w.x * bf16raw2f(u0.w) + w.y * bf16raw2f(u1.w)
                + w.z * bf16raw2f(u2.w) + w.w * bf16raw2f(u3.w);
      }
      ushort4 ou;
      ou.x = (unsigned short)bf16bits(acc[0]);
      ou.y = (unsigned short)bf16bits(acc[1]);
      ou.z = (unsigned short)bf16bits(acc[2]);
      ou.w = (unsigned short)bf16bits(acc[3]);
      *(ushort4*)(sAgg + (size_t)(tok0 + tl) * kAP + col) = ou;
    }
    __syncthreads();   // gather done; scratch reusable / sAgg rows published
  }

  // ---------------- phase 2: out = sAgg @ Wo^T + bo (no barriers) --------
  const int lane = t & 63, wave = t >> 6;
  const int r16 = lane & 15, quad = lane >> 4;
  const int wn = wave * 48;                    // 8 waves x 48 cols = 384
  float4v acc2[4][3];
  #pragma unroll
  for (int i = 0; i < 4; ++i)
    #pragma unroll
    for (int j = 0; j < 3; ++j) acc2[i][j] = (float4v){0.f, 0.f, 0.f, 0.f};

  const bf16* Bbase = Wot + (size_t)(wn + r16) * kD + quad * 8;

  #pragma unroll
  for (int kt = 0; kt < 12; ++kt) {
    const int k0 = kt * 32;
    short8 av[4];
    #pragma unroll
    for (int i = 0; i < 4; ++i)
      av[i] = *(const short8*)(sAgg + (size_t)(i * 16 + r16) * kAP + k0 + quad * 8);
    #pragma unroll
    for (int j = 0; j < 3; ++j) {
      const short8 bvj = *(const short8*)(Bbase + (size_t)(j * 16) * kD + k0);
      #pragma unroll
      for (int i = 0; i < 4; ++i)
        acc2[i][j] = __builtin_amdgcn_mfma_f32_16x16x32_bf16(av[i], bvj, acc2[i][j], 0, 0, 0);
    }
  }

  #pragma unroll
  for (int j = 0; j < 3; ++j) {
    const int col = wn + j * 16 + r16;
    const float bj = bo[col];
    #pragma unroll
    for (int i = 0; i < 4; ++i) {
      const int mb = m0 + i * 16 + quad * 4;
      #pragma unroll
      for (int r = 0; r < 4; ++r)
        out[(size_t)(mb + r) * kD + col] = acc2[i][j][r] + bj;
    }
  }
}

extern "C" void kernel_launch(void* const* d_in, const int* in_sizes, int n_in,
                              void* d_out, int out_size, void* d_ws, size_t ws_size,
                              hipStream_t stream)
{
  const float* query = (const float*)d_in[0];
  const float* value = (const float*)d_in[2];
  const float* Wv    = (const float*)d_in[7];
  const float* bv    = (const float*)d_in[8];
  const float* Woff  = (const float*)d_in[9];
  const float* boff  = (const float*)d_in[10];
  const float* Wwt   = (const float*)d_in[11];
  const float* bwt   = (const float*)d_in[12];
  const float* Wo    = (const float*)d_in[13];
  const float* bo    = (const float*)d_in[14];
  float* out = (float*)d_out;

  char* ws = (char*)d_ws;
  bf16*  Wvt  = (bf16*)(ws + oWvt);
  bf16*  Wot  = (bf16*)(ws + oWot);
  bf16*  Wch  = (bf16*)(ws + oWch);
  bf16*  Wcl  = (bf16*)(ws + oWcl);
  float* bcat = (float*)(ws + oBcat);
  bf16*  vB   = (bf16*)(ws + oVB);
  float* proj = (float*)(ws + oProj);

  const size_t prepN = nW + nW + nWcat + 96;
  prep_kernel<<<dim3((unsigned)((prepN + 255) / 256)), 256, 0, stream>>>(
      Wv, Wo, Woff, Wwt, boff, bwt, Wvt, Wot, Wch, Wcl, bcat);

  // vGEMM (768 blocks) + proj GEMM (256 blocks), LDS-free streaming
  fat_kernel<<<dim3(256 + 768), 256, 0, stream>>>(
      value, Wvt, bv, vB, query, Wch, Wcl, bcat, proj);

  // fused: coords + softmax + bilinear gather -> LDS agg -> out GEMM
  tail_kernel<<<dim3(512), 512, 0, stream>>>(proj, vB, Wot, bo, out);
}

// Round 4
// 267.508 us; speedup vs baseline: 1.1670x; 1.1670x over previous
//
#include <hip/hip_runtime.h>
#include <hip/hip_bf16.h>
#include <stdint.h>

using bf16 = __hip_bfloat16;

typedef __attribute__((ext_vector_type(8))) short short8;
typedef __attribute__((ext_vector_type(4))) float float4v;

namespace {
constexpr int kL  = 4096;
constexpr int kD  = 384;
constexpr int kGW = 64;
constexpr int kM  = 32768;
constexpr int kAP = 392;   // padded agg LDS stride (bf16): 784 B/row -> 2-way (free) banks

constexpr size_t nValue = (size_t)kM * kD;
constexpr size_t nW     = (size_t)kD * kD;
constexpr size_t nWcat  = (size_t)96 * kD;   // 96x384 (transposed cat weight)

// workspace offsets (bytes)
constexpr size_t oWvt  = 0;                                    // bf16 Wv^T [384][384]
constexpr size_t oWot  = oWvt  + nW * 2;                       // bf16 Wo^T [384][384]
constexpr size_t oWch  = oWot  + nW * 2;                       // bf16 Wcat^T hi [96][384]
constexpr size_t oWcl  = oWch  + nWcat * 2;                    // bf16 Wcat^T lo [96][384]
constexpr size_t oBcat = oWcl  + nWcat * 2;                    // f32 [96]
constexpr size_t oVB   = (oBcat + 96 * 4 + 255) & ~size_t(255);// bf16 v [kM][384]
constexpr size_t oProj = oVB   + nValue * 2;                   // f32 [kM][96]
}

__device__ __forceinline__ void load_lds_16(const void* g, void* l) {
  __builtin_amdgcn_global_load_lds((const __attribute__((address_space(1))) void*)g,
                                   (__attribute__((address_space(3))) void*)l,
                                   16, 0, 0);
}

__device__ __forceinline__ short bf16bits(float f) {
  bf16 h = __float2bfloat16(f);
  return *reinterpret_cast<short*>(&h);
}

__device__ __forceinline__ float bf16raw2f(unsigned short u) {
  union { unsigned int i; float f; } c;
  c.i = ((unsigned int)u) << 16;
  return c.f;
}

__device__ __forceinline__ short8 pack_hi8(const float4& f0, const float4& f1) {
  short8 hx;
  hx[0] = bf16bits(f0.x); hx[1] = bf16bits(f0.y);
  hx[2] = bf16bits(f0.z); hx[3] = bf16bits(f0.w);
  hx[4] = bf16bits(f1.x); hx[5] = bf16bits(f1.y);
  hx[6] = bf16bits(f1.z); hx[7] = bf16bits(f1.w);
  return hx;
}

__device__ __forceinline__ void pack_hilo8(const float4& f0, const float4& f1,
                                           short8& hx, short8& lx) {
  const float fv[8] = {f0.x, f0.y, f0.z, f0.w, f1.x, f1.y, f1.z, f1.w};
  #pragma unroll
  for (int q = 0; q < 8; ++q) {
    const bf16 h = __float2bfloat16(fv[q]);
    hx[q] = *reinterpret_cast<const short*>(&h);
    const bf16 lo = __float2bfloat16(fv[q] - __bfloat162float(h));
    lx[q] = *reinterpret_cast<const short*>(&lo);
  }
}

// -------------------------------------------------------------------------
// prep (weights only): Wv^T, Wo^T as bf16; Wcat^T split into hi/lo bf16 so
// the proj GEMM can run on MFMA with f32-level accuracy (err ~2^-17 rel).
// -------------------------------------------------------------------------
__global__ void prep_kernel(const float* __restrict__ Wv,
                            const float* __restrict__ Wo,
                            const float* __restrict__ Woff,
                            const float* __restrict__ Wwt,
                            const float* __restrict__ boff,
                            const float* __restrict__ bwt,
                            bf16* __restrict__ Wvt, bf16* __restrict__ Wot,
                            bf16* __restrict__ Wch, bf16* __restrict__ Wcl,
                            float* __restrict__ bcat)
{
  size_t i = (size_t)blockIdx.x * 256 + threadIdx.x;
  if (i < nW) {
    const int n = (int)(i / kD), k = (int)(i % kD);
    Wvt[i] = __float2bfloat16(Wv[(size_t)k * kD + n]);
    return;
  }
  i -= nW;
  if (i < nW) {
    const int n = (int)(i / kD), k = (int)(i % kD);
    Wot[i] = __float2bfloat16(Wo[(size_t)k * kD + n]);
    return;
  }
  i -= nW;
  if (i < nWcat) {
    const int n = (int)(i / kD), k = (int)(i % kD);
    const float val = (n < 64) ? Woff[(size_t)k * 64 + n] : Wwt[(size_t)k * 32 + (n - 64)];
    const bf16 h = __float2bfloat16(val);
    Wch[i] = h;
    Wcl[i] = __float2bfloat16(val - __bfloat162float(h));  // exact residual, then rounded
    return;
  }
  i -= nWcat;
  if (i < 96) bcat[i] = (i < 64) ? boff[i] : bwt[i - 64];
}

// -------------------------------------------------------------------------
// v GEMM body: vB[M,384] = value @ Wv + bv, bf16 out. r1 skeleton + two
// fixes driven by counters:
//  * BK=64 (6 K-steps) -> barrier-drains per block 24 -> 12. Accumulation
//    order unchanged (ks=0,1 walk k in the same sequence) -> bitwise-same.
//  * XOR bank-swizzle (chunk ^= row&7 within each 128 B row): kills the
//    8-way ds_read_b128 conflict (SQ_LDS_BANK_CONFLICT 1.87M in r1).
//    A: manual cast-stage writes to the swizzled slot. B: global_load_lds
//    keeps a LINEAR dest; the SOURCE address is pre-swizzled (rule #21).
// LDS = 32768 B exactly -> 5 blocks/CU (as r1's 28.7 KB gave).
// -------------------------------------------------------------------------
__device__ __forceinline__
void vgemm_body(char* smem, int bid,
                const float* __restrict__ A, const bf16* __restrict__ Bt,
                const float* __restrict__ bias, bf16* __restrict__ Cout)
{
  bf16* sA = (bf16*)smem;             // [128][64] bf16, swizzled, 16384 B
  bf16* sB = (bf16*)(smem + 16384);   // [128][64] bf16, swizzled, 16384 B
  const int tid  = threadIdx.x;
  const int lane = tid & 63;
  const int wave = tid >> 6;
  const int bm = bid / 3, bn = bid % 3;
  const int m0 = bm * 128, n0 = bn * 128;
  const int wm = (wave >> 1) * 64, wn = (wave & 1) * 64;
  const int r16 = lane & 15, quad = lane >> 4;

  float4v acc[4][4];
  #pragma unroll
  for (int i = 0; i < 4; ++i)
    #pragma unroll
    for (int j = 0; j < 4; ++j) acc[i][j] = (float4v){0.f, 0.f, 0.f, 0.f};

  for (int kt = 0; kt < 6; ++kt) {
    const int k0 = kt * 64;
    // stage A (f32 -> bf16 cast), swizzled ds_write
    #pragma unroll
    for (int r = 0; r < 4; ++r) {
      const int e = tid + r * 256;          // 0..1023
      const int row = e >> 3, j = e & 7;
      const float* src = A + (size_t)(m0 + row) * kD + k0 + j * 8;
      const float4 f0 = *(const float4*)src;
      const float4 f1 = *(const float4*)(src + 4);
      const int jw = j ^ (row & 7);
      *(short8*)(sA + row * 64 + jw * 8) = pack_hi8(f0, f1);
    }
    // stage B via global_load_lds: linear dest, pre-swizzled source
    #pragma unroll
    for (int r = 0; r < 4; ++r) {
      const int c = tid + r * 256;          // 0..1023
      const int row = c >> 3, j = c & 7;
      const int js = j ^ (row & 7);
      load_lds_16(Bt + (size_t)(n0 + row) * kD + k0 + js * 8, (char*)sB + c * 16);
    }
    __syncthreads();
    #pragma unroll
    for (int ks = 0; ks < 2; ++ks) {
      short8 av[4], bv[4];
      #pragma unroll
      for (int i = 0; i < 4; ++i) {
        const int row = wm + i * 16 + r16;
        const int ch = (ks * 4 + quad) ^ (row & 7);
        av[i] = *(const short8*)(sA + row * 64 + ch * 8);
      }
      #pragma unroll
      for (int j = 0; j < 4; ++j) {
        const int row = wn + j * 16 + r16;
        const int ch = (ks * 4 + quad) ^ (row & 7);
        bv[j] = *(const short8*)(sB + row * 64 + ch * 8);
      }
      #pragma unroll
      for (int i = 0; i < 4; ++i)
        #pragma unroll
        for (int j = 0; j < 4; ++j)
          acc[i][j] = __builtin_amdgcn_mfma_f32_16x16x32_bf16(av[i], bv[j], acc[i][j], 0, 0, 0);
    }
    __syncthreads();
  }

  #pragma unroll
  for (int j = 0; j < 4; ++j) {
    const int col = n0 + wn + j * 16 + r16;
    const float bj = bias[col];
    #pragma unroll
    for (int i = 0; i < 4; ++i) {
      const int mbase = m0 + wm + i * 16 + quad * 4;
      #pragma unroll
      for (int r = 0; r < 4; ++r)
        Cout[(size_t)(mbase + r) * kD + col] = __float2bfloat16(acc[i][j][r] + bj);
    }
  }
}

// -------------------------------------------------------------------------
// proj GEMM body (r1 split-bf16 MFMA skeleton, BK=32) + XOR swizzle
// (chunk ^= row&3 within each 64 B row): 8-way -> 4-way ds_read conflicts.
// acc = Ahi*Bhi + Ahi*Blo + Alo*Bhi (f32-level accuracy). Accumulation
// order identical to r1 -> bitwise-same proj output.
// -------------------------------------------------------------------------
__device__ __forceinline__
void proj_body(char* smem, int bid,
               const float* __restrict__ Q,
               const bf16* __restrict__ WhT, const bf16* __restrict__ WlT,
               const float* __restrict__ bc, float* __restrict__ proj)
{
  bf16* sAh = (bf16*)smem;             // [128][32] bf16 swz, 8192 B
  bf16* sAl = (bf16*)(smem + 8192);    // 8192 B
  bf16* sBh = (bf16*)(smem + 16384);   // [96][32] bf16 swz, 6144 B
  bf16* sBl = (bf16*)(smem + 22528);   // 6144 B -> total 28672
  const int tid  = threadIdx.x;
  const int lane = tid & 63;
  const int wave = tid >> 6;
  const int m0 = bid * 128;
  const int wm = (wave >> 1) * 64, wn = (wave & 1) * 48;
  const int r16 = lane & 15, quad = lane >> 4;

  float4v acc[4][3];
  #pragma unroll
  for (int i = 0; i < 4; ++i)
    #pragma unroll
    for (int j = 0; j < 3; ++j) acc[i][j] = (float4v){0.f, 0.f, 0.f, 0.f};

  for (int kt = 0; kt < 12; ++kt) {
    const int k0 = kt * 32;
    // stage A hi/lo (f32 -> bf16 pair), swizzled ds_write
    #pragma unroll
    for (int r = 0; r < 2; ++r) {
      const int e = tid + r * 256;          // 0..511
      const int row = e >> 2, j = e & 3;
      const float* src = Q + (size_t)(m0 + row) * kD + k0 + j * 8;
      const float4 f0 = *(const float4*)src;
      const float4 f1 = *(const float4*)(src + 4);
      short8 hx, lx;
      pack_hilo8(f0, f1, hx, lx);
      const int jw = j ^ (row & 3);
      *(short8*)(sAh + row * 32 + jw * 8) = hx;
      *(short8*)(sAl + row * 32 + jw * 8) = lx;
    }
    // stage B hi/lo via global_load_lds: linear dest, pre-swizzled source.
    // Branch boundary (tid=128) is a wave boundary -> dest stays
    // wave-uniform-base + lane*16.
    {
      int c = tid;                                    // hi chunks 0..255
      int row = c >> 2, j = c & 3, js = j ^ (row & 3);
      load_lds_16(WhT + (size_t)row * kD + k0 + js * 8, (char*)sBh + c * 16);
      if (tid < 128) {
        c = tid + 256;                                // hi chunks 256..383
        row = c >> 2; j = c & 3; js = j ^ (row & 3);
        load_lds_16(WhT + (size_t)row * kD + k0 + js * 8, (char*)sBh + c * 16);
      } else {
        c = tid - 128;                                // lo chunks 0..127
        row = c >> 2; j = c & 3; js = j ^ (row & 3);
        load_lds_16(WlT + (size_t)row * kD + k0 + js * 8, (char*)sBl + c * 16);
      }
      c = tid + 128;                                  // lo chunks 128..383
      row = c >> 2; j = c & 3; js = j ^ (row & 3);
      load_lds_16(WlT + (size_t)row * kD + k0 + js * 8, (char*)sBl + c * 16);
    }
    __syncthreads();

    short8 avh[4], avl[4];
    #pragma unroll
    for (int i = 0; i < 4; ++i) {
      const int row = wm + i * 16 + r16;
      const int ch = quad ^ (row & 3);
      avh[i] = *(const short8*)(sAh + row * 32 + ch * 8);
      avl[i] = *(const short8*)(sAl + row * 32 + ch * 8);
    }
    #pragma unroll
    for (int j = 0; j < 3; ++j) {
      const int row = wn + j * 16 + r16;
      const int ch = quad ^ (row & 3);
      const short8 bvh = *(const short8*)(sBh + row * 32 + ch * 8);
      const short8 bvl = *(const short8*)(sBl + row * 32 + ch * 8);
      #pragma unroll
      for (int i = 0; i < 4; ++i) {
        acc[i][j] = __builtin_amdgcn_mfma_f32_16x16x32_bf16(avh[i], bvh, acc[i][j], 0, 0, 0);
        acc[i][j] = __builtin_amdgcn_mfma_f32_16x16x32_bf16(avh[i], bvl, acc[i][j], 0, 0, 0);
        acc[i][j] = __builtin_amdgcn_mfma_f32_16x16x32_bf16(avl[i], bvh, acc[i][j], 0, 0, 0);
      }
    }
    __syncthreads();
  }

  #pragma unroll
  for (int j = 0; j < 3; ++j) {
    const int col = wn + j * 16 + r16;
    const float bj = bc[col];
    #pragma unroll
    for (int i = 0; i < 4; ++i) {
      const int mbase = m0 + wm + i * 16 + quad * 4;
      #pragma unroll
      for (int r = 0; r < 4; ++r)
        proj[(size_t)(mbase + r) * 96 + col] = acc[i][j][r] + bj;
    }
  }
}

// -------------------------------------------------------------------------
// Fat kernel: blocks [0,256) proj GEMM, [256,1024) v GEMM.
// smem = 32768 B exactly -> 5 blocks/CU (LDS-limited), as the best (r1)
// config had.
// -------------------------------------------------------------------------
__global__ __launch_bounds__(256)
void fat_kernel(const float* __restrict__ value, const bf16* __restrict__ Wvt,
                const float* __restrict__ bv,    bf16* __restrict__ vB,
                const float* __restrict__ Q,     const bf16* __restrict__ Wch,
                const bf16* __restrict__ Wcl,    const float* __restrict__ bcat,
                float* __restrict__ proj)
{
  __shared__ __align__(16) char smem[32768];
  const int pb = blockIdx.x;
  if (pb < 256) {
    proj_body(smem, pb, Q, Wch, Wcl, bcat, proj);
  } else {
    vgemm_body(smem, pb - 256, value, Wvt, bv, vB);
  }
}

// -------------------------------------------------------------------------
// tail kernel: fused sample + output GEMM. 512 blocks x 512 thr,
// 64 tokens/block, LDS 66,560 B -> 2 blocks/CU.
//  phase 1 (4 chunks of 16 tokens): coords+softmax -> scratch,
//    bilinear gather (softmax wt premultiplied) -> sAgg[64][392] bf16.
//  phase 2: out[64][384] = sAgg @ Wo^T + bo. A from LDS (2-way free
//    banks via 392 stride), B frags direct from L2 (Wo^T 288 KB hot;
//    each wave owns a distinct 48-col slice) -> no barriers at all.
// XCD swizzle: chunk = (raw%8)*64 + raw/8 -> each XCD owns exactly one
// batch's v slice (3.1 MB, L2-resident).
// -------------------------------------------------------------------------
__global__ __launch_bounds__(512)
void tail_kernel(const float* __restrict__ proj, const bf16* __restrict__ v,
                 const bf16* __restrict__ Wot, const float* __restrict__ bo,
                 float* __restrict__ out)
{
  __shared__ __align__(16) char smem[66560];
  bf16*   sAgg  = (bf16*)smem;                 // [64][392] = 50176 B
  int4*   scoff = (int4*)(smem + 50176);       // [512] = 8192 B
  float4* scw   = (float4*)(smem + 58368);     // [512] = 8192 B

  const int raw   = blockIdx.x;
  const int chunk = (raw & 7) * 64 + (raw >> 3);
  const int m0    = chunk * 64;
  const int b     = m0 >> 12;
  const int l0    = m0 & 4095;
  const int t     = threadIdx.x;

  // ---------------- phase 1: sample ----------------
  for (int ct = 0; ct < 4; ++ct) {
    const int tok0 = ct * 16;
    {
      const int tl = t >> 5, pt = t & 31;      // 16 tok x 32 pts, 1/thread
      const int tok = tok0 + tl;
      const int l   = l0 + tok;
      const float* pb_ = proj + (size_t)(m0 + tok) * 96;
      const float2 off = *(const float2*)(pb_ + 2 * pt);
      const int h = pt >> 2, p = pt & 3;
      const float4 lg = *(const float4*)(pb_ + 64 + h * 4);
      const float g[4] = {lg.x, lg.y, lg.z, lg.w};
      const float mx = fmaxf(fmaxf(g[0], g[1]), fmaxf(g[2], g[3]));
      float e[4], sum = 0.f;
      #pragma unroll
      for (int jj = 0; jj < 4; ++jj) { e[jj] = expf(g[jj] - mx); sum += e[jj]; }
      const float wt = e[p] / sum;
      const float refx = (float)(l & 63) * (1.0f / 63.0f);
      const float refy = (float)(l >> 6) * (1.0f / 63.0f);
      const float locx = fminf(fmaxf(refx + off.x, 0.f), 1.f);
      const float locy = fminf(fmaxf(refy + off.y, 0.f), 1.f);
      const float ph = locx * 63.0f;           // faithful: component 0 -> row coord
      const float pw = locy * 63.0f;
      const float fy = floorf(ph), fx = floorf(pw);
      const int y0 = (int)fy, x0 = (int)fx;
      const int y1 = min(y0 + 1, 63), x1 = min(x0 + 1, 63);
      const float wy = ph - fy, wx = pw - fx;
      scoff[tl * 32 + pt] = make_int4((y0 * kGW + x0) * kD, (y0 * kGW + x1) * kD,
                                      (y1 * kGW + x0) * kD, (y1 * kGW + x1) * kD);
      scw[tl * 32 + pt] = make_float4(wt * (1.f - wy) * (1.f - wx), wt * (1.f - wy) * wx,
                                      wt * wy * (1.f - wx),         wt * wy * wx);
    }
    __syncthreads();
    #pragma unroll
    for (int it = 0; it < 3; ++it) {
      const int task = t + it * 512;           // 0..1535 = 16 tok x 96
      const int tl = task / 96;
      const int q  = task - tl * 96;
      const int h  = q / 12;
      const int col = q * 4;                   // = h*48 + (q%12)*4
      const unsigned short* vb = (const unsigned short*)(v + (size_t)b * kL * kD + col);
      float4v acc = (float4v){0.f, 0.f, 0.f, 0.f};
      #pragma unroll
      for (int p = 0; p < 4; ++p) {
        const int4   o = scoff[tl * 32 + h * 4 + p];
        const float4 w = scw  [tl * 32 + h * 4 + p];
        const ushort4 u0 = *(const ushort4*)(vb + o.x);
        const ushort4 u1 = *(const ushort4*)(vb + o.y);
        const ushort4 u2 = *(const ushort4*)(vb + o.z);
        const ushort4 u3 = *(const ushort4*)(vb + o.w);
        acc[0] += w.x * bf16raw2f(u0.x) + w.y * bf16raw2f(u1.x)
                + w.z * bf16raw2f(u2.x) + w.w * bf16raw2f(u3.x);
        acc[1] += w.x * bf16raw2f(u0.y) + w.y * bf16raw2f(u1.y)
                + w.z * bf16raw2f(u2.y) + w.w * bf16raw2f(u3.y);
        acc[2] += w.x * bf16raw2f(u0.z) + w.y * bf16raw2f(u1.z)
                + w.z * bf16raw2f(u2.z) + w.w * bf16raw2f(u3.z);
        acc[3] += w.x * bf16raw2f(u0.w) + w.y * bf16raw2f(u1.w)
                + w.z * bf16raw2f(u2.w) + w.w * bf16raw2f(u3.w);
      }
      ushort4 ou;
      ou.x = (unsigned short)bf16bits(acc[0]);
      ou.y = (unsigned short)bf16bits(acc[1]);
      ou.z = (unsigned short)bf16bits(acc[2]);
      ou.w = (unsigned short)bf16bits(acc[3]);
      *(ushort4*)(sAgg + (size_t)(tok0 + tl) * kAP + col) = ou;
    }
    __syncthreads();   // gather done; scratch reusable / sAgg rows published
  }

  // ---------------- phase 2: out = sAgg @ Wo^T + bo (no barriers) --------
  const int lane = t & 63, wave = t >> 6;
  const int r16 = lane & 15, quad = lane >> 4;
  const int wn = wave * 48;                    // 8 waves x 48 cols = 384
  float4v acc2[4][3];
  #pragma unroll
  for (int i = 0; i < 4; ++i)
    #pragma unroll
    for (int j = 0; j < 3; ++j) acc2[i][j] = (float4v){0.f, 0.f, 0.f, 0.f};

  const bf16* Bbase = Wot + (size_t)(wn + r16) * kD + quad * 8;

  #pragma unroll
  for (int kt = 0; kt < 12; ++kt) {
    const int k0 = kt * 32;
    short8 av[4];
    #pragma unroll
    for (int i = 0; i < 4; ++i)
      av[i] = *(const short8*)(sAgg + (size_t)(i * 16 + r16) * kAP + k0 + quad * 8);
    #pragma unroll
    for (int j = 0; j < 3; ++j) {
      const short8 bvj = *(const short8*)(Bbase + (size_t)(j * 16) * kD + k0);
      #pragma unroll
      for (int i = 0; i < 4; ++i)
        acc2[i][j] = __builtin_amdgcn_mfma_f32_16x16x32_bf16(av[i], bvj, acc2[i][j], 0, 0, 0);
    }
  }

  #pragma unroll
  for (int j = 0; j < 3; ++j) {
    const int col = wn + j * 16 + r16;
    const float bj = bo[col];
    #pragma unroll
    for (int i = 0; i < 4; ++i) {
      const int mb = m0 + i * 16 + quad * 4;
      #pragma unroll
      for (int r = 0; r < 4; ++r)
        out[(size_t)(mb + r) * kD + col] = acc2[i][j][r] + bj;
    }
  }
}

extern "C" void kernel_launch(void* const* d_in, const int* in_sizes, int n_in,
                              void* d_out, int out_size, void* d_ws, size_t ws_size,
                              hipStream_t stream)
{
  const float* query = (const float*)d_in[0];
  const float* value = (const float*)d_in[2];
  const float* Wv    = (const float*)d_in[7];
  const float* bv    = (const float*)d_in[8];
  const float* Woff  = (const float*)d_in[9];
  const float* boff  = (const float*)d_in[10];
  const float* Wwt   = (const float*)d_in[11];
  const float* bwt   = (const float*)d_in[12];
  const float* Wo    = (const float*)d_in[13];
  const float* bo    = (const float*)d_in[14];
  float* out = (float*)d_out;

  char* ws = (char*)d_ws;
  bf16*  Wvt  = (bf16*)(ws + oWvt);
  bf16*  Wot  = (bf16*)(ws + oWot);
  bf16*  Wch  = (bf16*)(ws + oWch);
  bf16*  Wcl  = (bf16*)(ws + oWcl);
  float* bcat = (float*)(ws + oBcat);
  bf16*  vB   = (bf16*)(ws + oVB);
  float* proj = (float*)(ws + oProj);

  const size_t prepN = nW + nW + nWcat + 96;
  prep_kernel<<<dim3((unsigned)((prepN + 255) / 256)), 256, 0, stream>>>(
      Wv, Wo, Woff, Wwt, boff, bwt, Wvt, Wot, Wch, Wcl, bcat);

  // vGEMM (768 blocks, BK=64) + proj GEMM (256 blocks, BK=32), swizzled LDS
  fat_kernel<<<dim3(256 + 768), 256, 0, stream>>>(
      value, Wvt, bv, vB, query, Wch, Wcl, bcat, proj);

  // fused: coords + softmax + bilinear gather -> LDS agg -> out GEMM
  tail_kernel<<<dim3(512), 512, 0, stream>>>(proj, vB, Wot, bo, out);
}

// Round 5
// 264.931 us; speedup vs baseline: 1.1783x; 1.0097x over previous
//
#include <hip/hip_runtime.h>
#include <hip/hip_bf16.h>
#include <stdint.h>

using bf16 = __hip_bfloat16;

typedef __attribute__((ext_vector_type(8))) short short8;
typedef __attribute__((ext_vector_type(4))) float float4v;

namespace {
constexpr int kL  = 4096;
constexpr int kD  = 384;
constexpr int kGW = 64;
constexpr int kM  = 32768;
constexpr int kAP = 392;   // padded agg LDS stride (bf16): 784 B/row -> 2-way (free) banks

constexpr size_t nValue = (size_t)kM * kD;
constexpr size_t nW     = (size_t)kD * kD;
constexpr size_t nWcat  = (size_t)96 * kD;   // 96x384 (transposed cat weight)

// workspace offsets (bytes)
constexpr size_t oWvt  = 0;                                    // bf16 Wv^T [384][384]
constexpr size_t oWot  = oWvt  + nW * 2;                       // bf16 Wo^T [384][384]
constexpr size_t oWch  = oWot  + nW * 2;                       // bf16 Wcat^T hi [96][384]
constexpr size_t oWcl  = oWch  + nWcat * 2;                    // bf16 Wcat^T lo [96][384]
constexpr size_t oBcat = oWcl  + nWcat * 2;                    // f32 [96]
constexpr size_t oVB   = (oBcat + 96 * 4 + 255) & ~size_t(255);// bf16 v [kM][384]
constexpr size_t oProj = oVB   + nValue * 2;                   // f32 [kM][96]
}

__device__ __forceinline__ void load_lds_16(const void* g, void* l) {
  __builtin_amdgcn_global_load_lds((const __attribute__((address_space(1))) void*)g,
                                   (__attribute__((address_space(3))) void*)l,
                                   16, 0, 0);
}

__device__ __forceinline__ short bf16bits(float f) {
  bf16 h = __float2bfloat16(f);
  return *reinterpret_cast<short*>(&h);
}

__device__ __forceinline__ float bf16raw2f(unsigned short u) {
  union { unsigned int i; float f; } c;
  c.i = ((unsigned int)u) << 16;
  return c.f;
}

__device__ __forceinline__ short8 pack_hi8(const float4& f0, const float4& f1) {
  short8 hx;
  hx[0] = bf16bits(f0.x); hx[1] = bf16bits(f0.y);
  hx[2] = bf16bits(f0.z); hx[3] = bf16bits(f0.w);
  hx[4] = bf16bits(f1.x); hx[5] = bf16bits(f1.y);
  hx[6] = bf16bits(f1.z); hx[7] = bf16bits(f1.w);
  return hx;
}

__device__ __forceinline__ void pack_hilo8(const float4& f0, const float4& f1,
                                           short8& hx, short8& lx) {
  const float fv[8] = {f0.x, f0.y, f0.z, f0.w, f1.x, f1.y, f1.z, f1.w};
  #pragma unroll
  for (int q = 0; q < 8; ++q) {
    const bf16 h = __float2bfloat16(fv[q]);
    hx[q] = *reinterpret_cast<const short*>(&h);
    const bf16 lo = __float2bfloat16(fv[q] - __bfloat162float(h));
    lx[q] = *reinterpret_cast<const short*>(&lo);
  }
}

// -------------------------------------------------------------------------
// prep (weights only): Wv^T, Wo^T as bf16; Wcat^T split into hi/lo bf16 so
// the proj GEMM can run on MFMA with f32-level accuracy (err ~2^-17 rel).
// -------------------------------------------------------------------------
__global__ void prep_kernel(const float* __restrict__ Wv,
                            const float* __restrict__ Wo,
                            const float* __restrict__ Woff,
                            const float* __restrict__ Wwt,
                            const float* __restrict__ boff,
                            const float* __restrict__ bwt,
                            bf16* __restrict__ Wvt, bf16* __restrict__ Wot,
                            bf16* __restrict__ Wch, bf16* __restrict__ Wcl,
                            float* __restrict__ bcat)
{
  size_t i = (size_t)blockIdx.x * 256 + threadIdx.x;
  if (i < nW) {
    const int n = (int)(i / kD), k = (int)(i % kD);
    Wvt[i] = __float2bfloat16(Wv[(size_t)k * kD + n]);
    return;
  }
  i -= nW;
  if (i < nW) {
    const int n = (int)(i / kD), k = (int)(i % kD);
    Wot[i] = __float2bfloat16(Wo[(size_t)k * kD + n]);
    return;
  }
  i -= nW;
  if (i < nWcat) {
    const int n = (int)(i / kD), k = (int)(i % kD);
    const float val = (n < 64) ? Woff[(size_t)k * 64 + n] : Wwt[(size_t)k * 32 + (n - 64)];
    const bf16 h = __float2bfloat16(val);
    Wch[i] = h;
    Wcl[i] = __float2bfloat16(val - __bfloat162float(h));  // exact residual, then rounded
    return;
  }
  i -= nWcat;
  if (i < 96) bcat[i] = (i < 64) ? boff[i] : bwt[i - 64];
}

// -------------------------------------------------------------------------
// v GEMM body: vB[M,384] = value @ Wv + bv, bf16 out.
// m248 2-phase dbuf at FULL occupancy (the r2 schedule, but 32 KB not 57):
//  per kt: issue A-glb loads(kt+1) + B-DMA(kt+1,nxt) FIRST, then ds_read +
//  MFMA on buf[cur] (hides load latency), then cast+write A(nxt), ONE
//  __syncthreads per kt. BK=32, LDS = 2x(8K A + 8K B) = 32768 -> 5 blk/CU.
// Swizzle ((row>>1)&3) on 64B rows: 8 bank-groups over 16 frag rows ->
//  2-way (free). Write side + read side use the same XOR (rule #21);
//  B keeps LINEAR gload_lds dest with pre-swizzled global source.
// -------------------------------------------------------------------------
__device__ __forceinline__
void vgemm_body(char* smem, int bid,
                const float* __restrict__ A, const bf16* __restrict__ Bt,
                const float* __restrict__ bias, bf16* __restrict__ Cout)
{
  bf16* sA = (bf16*)smem;             // [2][128][32] bf16 swz, 8192 B/buf
  char* sBB = smem + 16384;           // [2][128][32] bf16, 8192 B/buf
  const int tid  = threadIdx.x;
  const int lane = tid & 63;
  const int wave = tid >> 6;
  const int bm = bid / 3, bn = bid % 3;
  const int m0 = bm * 128, n0 = bn * 128;
  const int wm = (wave >> 1) * 64, wn = (wave & 1) * 64;
  const int r16 = lane & 15, quad = lane >> 4;

  float4v acc[4][4];
  #pragma unroll
  for (int i = 0; i < 4; ++i)
    #pragma unroll
    for (int j = 0; j < 4; ++j) acc[i][j] = (float4v){0.f, 0.f, 0.f, 0.f};

  // two 16B-granule slots per thread (512 granules per tile)
  const int e0 = tid, e1 = tid + 256;
  const int rA0 = e0 >> 2, gA0 = e0 & 3;
  const int rA1 = e1 >> 2, gA1 = e1 & 3;
  const int wA0 = rA0 * 32 + (gA0 ^ ((rA0 >> 1) & 3)) * 8;  // bf16-elem offset
  const int wA1 = rA1 * 32 + (gA1 ^ ((rA1 >> 1) & 3)) * 8;
  const int sBc0 = (gA0 ^ ((rA0 >> 1) & 3)) * 8;            // swizzled src col
  const int sBc1 = (gA1 ^ ((rA1 >> 1) & 3)) * 8;

  float4 f00, f01, f10, f11;
  auto loadA = [&](int k0) {
    const float* s0 = A + (size_t)(m0 + rA0) * kD + k0 + gA0 * 8;
    f00 = *(const float4*)s0; f01 = *(const float4*)(s0 + 4);
    const float* s1 = A + (size_t)(m0 + rA1) * kD + k0 + gA1 * 8;
    f10 = *(const float4*)s1; f11 = *(const float4*)(s1 + 4);
  };
  auto writeA = [&](int buf) {
    *(short8*)(sA + buf * 4096 + wA0) = pack_hi8(f00, f01);
    *(short8*)(sA + buf * 4096 + wA1) = pack_hi8(f10, f11);
  };
  auto stageB = [&](int k0, int buf) {
    load_lds_16(Bt + (size_t)(n0 + rA0) * kD + k0 + sBc0, sBB + buf * 8192 + e0 * 16);
    load_lds_16(Bt + (size_t)(n0 + rA1) * kD + k0 + sBc1, sBB + buf * 8192 + e1 * 16);
  };

  loadA(0);
  stageB(0, 0);
  writeA(0);
  __syncthreads();

  for (int kt = 0; kt < 12; ++kt) {
    const int cur = kt & 1, nxt = cur ^ 1;
    if (kt < 11) {
      loadA((kt + 1) * 32);
      stageB((kt + 1) * 32, nxt);
    }
    const bf16* sAc = sA + cur * 4096;
    const bf16* sBc = (const bf16*)(sBB + cur * 8192);
    short8 av[4], bv[4];
    #pragma unroll
    for (int i = 0; i < 4; ++i) {
      const int row = wm + i * 16 + r16;
      av[i] = *(const short8*)(sAc + row * 32 + (quad ^ ((row >> 1) & 3)) * 8);
    }
    #pragma unroll
    for (int j = 0; j < 4; ++j) {
      const int row = wn + j * 16 + r16;
      bv[j] = *(const short8*)(sBc + row * 32 + (quad ^ ((row >> 1) & 3)) * 8);
    }
    #pragma unroll
    for (int i = 0; i < 4; ++i)
      #pragma unroll
      for (int j = 0; j < 4; ++j)
        acc[i][j] = __builtin_amdgcn_mfma_f32_16x16x32_bf16(av[i], bv[j], acc[i][j], 0, 0, 0);
    if (kt < 11) {
      writeA(nxt);
      __syncthreads();
    }
  }

  #pragma unroll
  for (int j = 0; j < 4; ++j) {
    const int col = n0 + wn + j * 16 + r16;
    const float bj = bias[col];
    #pragma unroll
    for (int i = 0; i < 4; ++i) {
      const int mbase = m0 + wm + i * 16 + quad * 4;
      #pragma unroll
      for (int r = 0; r < 4; ++r)
        Cout[(size_t)(mbase + r) * kD + col] = __float2bfloat16(acc[i][j][r] + bj);
    }
  }
}

// -------------------------------------------------------------------------
// proj GEMM body (r4 single-buf skeleton, BK=32) with the upgraded
// ((row>>1)&3) swizzle -> 2-way (free) instead of 4-way.
// acc = Ahi*Bhi + Ahi*Blo + Alo*Bhi (f32-level accuracy).
// -------------------------------------------------------------------------
__device__ __forceinline__
void proj_body(char* smem, int bid,
               const float* __restrict__ Q,
               const bf16* __restrict__ WhT, const bf16* __restrict__ WlT,
               const float* __restrict__ bc, float* __restrict__ proj)
{
  bf16* sAh = (bf16*)smem;             // [128][32] bf16 swz, 8192 B
  bf16* sAl = (bf16*)(smem + 8192);    // 8192 B
  bf16* sBh = (bf16*)(smem + 16384);   // [96][32] bf16 swz, 6144 B
  bf16* sBl = (bf16*)(smem + 22528);   // 6144 B -> total 28672
  const int tid  = threadIdx.x;
  const int lane = tid & 63;
  const int wave = tid >> 6;
  const int m0 = bid * 128;
  const int wm = (wave >> 1) * 64, wn = (wave & 1) * 48;
  const int r16 = lane & 15, quad = lane >> 4;

  float4v acc[4][3];
  #pragma unroll
  for (int i = 0; i < 4; ++i)
    #pragma unroll
    for (int j = 0; j < 3; ++j) acc[i][j] = (float4v){0.f, 0.f, 0.f, 0.f};

  for (int kt = 0; kt < 12; ++kt) {
    const int k0 = kt * 32;
    // stage A hi/lo (f32 -> bf16 pair), swizzled ds_write
    #pragma unroll
    for (int r = 0; r < 2; ++r) {
      const int e = tid + r * 256;          // 0..511
      const int row = e >> 2, j = e & 3;
      const float* src = Q + (size_t)(m0 + row) * kD + k0 + j * 8;
      const float4 f0 = *(const float4*)src;
      const float4 f1 = *(const float4*)(src + 4);
      short8 hx, lx;
      pack_hilo8(f0, f1, hx, lx);
      const int jw = j ^ ((row >> 1) & 3);
      *(short8*)(sAh + row * 32 + jw * 8) = hx;
      *(short8*)(sAl + row * 32 + jw * 8) = lx;
    }
    // stage B hi/lo via global_load_lds: linear dest, pre-swizzled source.
    // Branch boundary (tid=128) is a wave boundary -> dest stays
    // wave-uniform-base + lane*16.
    {
      int c = tid;                                    // hi chunks 0..255
      int row = c >> 2, j = c & 3, js = j ^ ((row >> 1) & 3);
      load_lds_16(WhT + (size_t)row * kD + k0 + js * 8, (char*)sBh + c * 16);
      if (tid < 128) {
        c = tid + 256;                                // hi chunks 256..383
        row = c >> 2; j = c & 3; js = j ^ ((row >> 1) & 3);
        load_lds_16(WhT + (size_t)row * kD + k0 + js * 8, (char*)sBh + c * 16);
      } else {
        c = tid - 128;                                // lo chunks 0..127
        row = c >> 2; j = c & 3; js = j ^ ((row >> 1) & 3);
        load_lds_16(WlT + (size_t)row * kD + k0 + js * 8, (char*)sBl + c * 16);
      }
      c = tid + 128;                                  // lo chunks 128..383
      row = c >> 2; j = c & 3; js = j ^ ((row >> 1) & 3);
      load_lds_16(WlT + (size_t)row * kD + k0 + js * 8, (char*)sBl + c * 16);
    }
    __syncthreads();

    short8 avh[4], avl[4];
    #pragma unroll
    for (int i = 0; i < 4; ++i) {
      const int row = wm + i * 16 + r16;
      const int ch = quad ^ ((row >> 1) & 3);
      avh[i] = *(const short8*)(sAh + row * 32 + ch * 8);
      avl[i] = *(const short8*)(sAl + row * 32 + ch * 8);
    }
    #pragma unroll
    for (int j = 0; j < 3; ++j) {
      const int row = wn + j * 16 + r16;
      const int ch = quad ^ ((row >> 1) & 3);
      const short8 bvh = *(const short8*)(sBh + row * 32 + ch * 8);
      const short8 bvl = *(const short8*)(sBl + row * 32 + ch * 8);
      #pragma unroll
      for (int i = 0; i < 4; ++i) {
        acc[i][j] = __builtin_amdgcn_mfma_f32_16x16x32_bf16(avh[i], bvh, acc[i][j], 0, 0, 0);
        acc[i][j] = __builtin_amdgcn_mfma_f32_16x16x32_bf16(avh[i], bvl, acc[i][j], 0, 0, 0);
        acc[i][j] = __builtin_amdgcn_mfma_f32_16x16x32_bf16(avl[i], bvh, acc[i][j], 0, 0, 0);
      }
    }
    __syncthreads();
  }

  #pragma unroll
  for (int j = 0; j < 3; ++j) {
    const int col = wn + j * 16 + r16;
    const float bj = bc[col];
    #pragma unroll
    for (int i = 0; i < 4; ++i) {
      const int mbase = m0 + wm + i * 16 + quad * 4;
      #pragma unroll
      for (int r = 0; r < 4; ++r)
        proj[(size_t)(mbase + r) * 96 + col] = acc[i][j][r] + bj;
    }
  }
}

// -------------------------------------------------------------------------
// Fat kernel: blocks [0,256) proj GEMM, [256,1024) v GEMM.
// smem = 32768 B -> 5 blocks/CU (LDS-limited).
// -------------------------------------------------------------------------
__global__ __launch_bounds__(256)
void fat_kernel(const float* __restrict__ value, const bf16* __restrict__ Wvt,
                const float* __restrict__ bv,    bf16* __restrict__ vB,
                const float* __restrict__ Q,     const bf16* __restrict__ Wch,
                const bf16* __restrict__ Wcl,    const float* __restrict__ bcat,
                float* __restrict__ proj)
{
  __shared__ __align__(16) char smem[32768];
  const int pb = blockIdx.x;
  if (pb < 256) {
    proj_body(smem, pb, Q, Wch, Wcl, bcat, proj);
  } else {
    vgemm_body(smem, pb - 256, value, Wvt, bv, vB);
  }
}

// -------------------------------------------------------------------------
// tail kernel: fused sample + output GEMM. 512 blocks x 512 thr,
// 64 tokens/block, LDS 66,560 B -> 2 blocks/CU.
//  phase 1 (4 chunks of 16 tokens): coords+softmax -> scratch,
//    bilinear gather (softmax wt premultiplied) -> sAgg[64][392] bf16.
//  phase 2: out[64][384] = sAgg @ Wo^T + bo. A from LDS (2-way free
//    banks via 392 stride), B frags direct from L2 (Wo^T 288 KB hot;
//    each wave owns a distinct 48-col slice) -> no barriers at all.
// XCD swizzle: chunk = (raw%8)*64 + raw/8 -> each XCD owns exactly one
// batch's v slice (3.1 MB, L2-resident).
// -------------------------------------------------------------------------
__global__ __launch_bounds__(512)
void tail_kernel(const float* __restrict__ proj, const bf16* __restrict__ v,
                 const bf16* __restrict__ Wot, const float* __restrict__ bo,
                 float* __restrict__ out)
{
  __shared__ __align__(16) char smem[66560];
  bf16*   sAgg  = (bf16*)smem;                 // [64][392] = 50176 B
  int4*   scoff = (int4*)(smem + 50176);       // [512] = 8192 B
  float4* scw   = (float4*)(smem + 58368);     // [512] = 8192 B

  const int raw   = blockIdx.x;
  const int chunk = (raw & 7) * 64 + (raw >> 3);
  const int m0    = chunk * 64;
  const int b     = m0 >> 12;
  const int l0    = m0 & 4095;
  const int t     = threadIdx.x;

  // ---------------- phase 1: sample ----------------
  for (int ct = 0; ct < 4; ++ct) {
    const int tok0 = ct * 16;
    {
      const int tl = t >> 5, pt = t & 31;      // 16 tok x 32 pts, 1/thread
      const int tok = tok0 + tl;
      const int l   = l0 + tok;
      const float* pb_ = proj + (size_t)(m0 + tok) * 96;
      const float2 off = *(const float2*)(pb_ + 2 * pt);
      const int h = pt >> 2, p = pt & 3;
      const float4 lg = *(const float4*)(pb_ + 64 + h * 4);
      const float g[4] = {lg.x, lg.y, lg.z, lg.w};
      const float mx = fmaxf(fmaxf(g[0], g[1]), fmaxf(g[2], g[3]));
      float e[4], sum = 0.f;
      #pragma unroll
      for (int jj = 0; jj < 4; ++jj) { e[jj] = expf(g[jj] - mx); sum += e[jj]; }
      const float wt = e[p] / sum;
      const float refx = (float)(l & 63) * (1.0f / 63.0f);
      const float refy = (float)(l >> 6) * (1.0f / 63.0f);
      const float locx = fminf(fmaxf(refx + off.x, 0.f), 1.f);
      const float locy = fminf(fmaxf(refy + off.y, 0.f), 1.f);
      const float ph = locx * 63.0f;           // faithful: component 0 -> row coord
      const float pw = locy * 63.0f;
      const float fy = floorf(ph), fx = floorf(pw);
      const int y0 = (int)fy, x0 = (int)fx;
      const int y1 = min(y0 + 1, 63), x1 = min(x0 + 1, 63);
      const float wy = ph - fy, wx = pw - fx;
      scoff[tl * 32 + pt] = make_int4((y0 * kGW + x0) * kD, (y0 * kGW + x1) * kD,
                                      (y1 * kGW + x0) * kD, (y1 * kGW + x1) * kD);
      scw[tl * 32 + pt] = make_float4(wt * (1.f - wy) * (1.f - wx), wt * (1.f - wy) * wx,
                                      wt * wy * (1.f - wx),         wt * wy * wx);
    }
    __syncthreads();
    #pragma unroll
    for (int it = 0; it < 3; ++it) {
      const int task = t + it * 512;           // 0..1535 = 16 tok x 96
      const int tl = task / 96;
      const int q  = task - tl * 96;
      const int h  = q / 12;
      const int col = q * 4;                   // = h*48 + (q%12)*4
      const unsigned short* vb = (const unsigned short*)(v + (size_t)b * kL * kD + col);
      float4v acc = (float4v){0.f, 0.f, 0.f, 0.f};
      #pragma unroll
      for (int p = 0; p < 4; ++p) {
        const int4   o = scoff[tl * 32 + h * 4 + p];
        const float4 w = scw  [tl * 32 + h * 4 + p];
        const ushort4 u0 = *(const ushort4*)(vb + o.x);
        const ushort4 u1 = *(const ushort4*)(vb + o.y);
        const ushort4 u2 = *(const ushort4*)(vb + o.z);
        const ushort4 u3 = *(const ushort4*)(vb + o.w);
        acc[0] += w.x * bf16raw2f(u0.x) + w.y * bf16raw2f(u1.x)
                + w.z * bf16raw2f(u2.x) + w.w * bf16raw2f(u3.x);
        acc[1] += w.x * bf16raw2f(u0.y) + w.y * bf16raw2f(u1.y)
                + w.z * bf16raw2f(u2.y) + w.w * bf16raw2f(u3.y);
        acc[2] += w.x * bf16raw2f(u0.z) + w.y * bf16raw2f(u1.z)
                + w.z * bf16raw2f(u2.z) + w.w * bf16raw2f(u3.z);
        acc[3] += w.x * bf16raw2f(u0.w) + w.y * bf16raw2f(u1.w)
                + w.z * bf16raw2f(u2.w) + w.w * bf16raw2f(u3.w);
      }
      ushort4 ou;
      ou.x = (unsigned short)bf16bits(acc[0]);
      ou.y = (unsigned short)bf16bits(acc[1]);
      ou.z = (unsigned short)bf16bits(acc[2]);
      ou.w = (unsigned short)bf16bits(acc[3]);
      *(ushort4*)(sAgg + (size_t)(tok0 + tl) * kAP + col) = ou;
    }
    __syncthreads();   // gather done; scratch reusable / sAgg rows published
  }

  // ---------------- phase 2: out = sAgg @ Wo^T + bo (no barriers) --------
  const int lane = t & 63, wave = t >> 6;
  const int r16 = lane & 15, quad = lane >> 4;
  const int wn = wave * 48;                    // 8 waves x 48 cols = 384
  float4v acc2[4][3];
  #pragma unroll
  for (int i = 0; i < 4; ++i)
    #pragma unroll
    for (int j = 0; j < 3; ++j) acc2[i][j] = (float4v){0.f, 0.f, 0.f, 0.f};

  const bf16* Bbase = Wot + (size_t)(wn + r16) * kD + quad * 8;

  #pragma unroll
  for (int kt = 0; kt < 12; ++kt) {
    const int k0 = kt * 32;
    short8 av[4];
    #pragma unroll
    for (int i = 0; i < 4; ++i)
      av[i] = *(const short8*)(sAgg + (size_t)(i * 16 + r16) * kAP + k0 + quad * 8);
    #pragma unroll
    for (int j = 0; j < 3; ++j) {
      const short8 bvj = *(const short8*)(Bbase + (size_t)(j * 16) * kD + k0);
      #pragma unroll
      for (int i = 0; i < 4; ++i)
        acc2[i][j] = __builtin_amdgcn_mfma_f32_16x16x32_bf16(av[i], bvj, acc2[i][j], 0, 0, 0);
    }
  }

  #pragma unroll
  for (int j = 0; j < 3; ++j) {
    const int col = wn + j * 16 + r16;
    const float bj = bo[col];
    #pragma unroll
    for (int i = 0; i < 4; ++i) {
      const int mb = m0 + i * 16 + quad * 4;
      #pragma unroll
      for (int r = 0; r < 4; ++r)
        out[(size_t)(mb + r) * kD + col] = acc2[i][j][r] + bj;
    }
  }
}

extern "C" void kernel_launch(void* const* d_in, const int* in_sizes, int n_in,
                              void* d_out, int out_size, void* d_ws, size_t ws_size,
                              hipStream_t stream)
{
  const float* query = (const float*)d_in[0];
  const float* value = (const float*)d_in[2];
  const float* Wv    = (const float*)d_in[7];
  const float* bv    = (const float*)d_in[8];
  const float* Woff  = (const float*)d_in[9];
  const float* boff  = (const float*)d_in[10];
  const float* Wwt   = (const float*)d_in[11];
  const float* bwt   = (const float*)d_in[12];
  const float* Wo    = (const float*)d_in[13];
  const float* bo    = (const float*)d_in[14];
  float* out = (float*)d_out;

  char* ws = (char*)d_ws;
  bf16*  Wvt  = (bf16*)(ws + oWvt);
  bf16*  Wot  = (bf16*)(ws + oWot);
  bf16*  Wch  = (bf16*)(ws + oWch);
  bf16*  Wcl  = (bf16*)(ws + oWcl);
  float* bcat = (float*)(ws + oBcat);
  bf16*  vB   = (bf16*)(ws + oVB);
  float* proj = (float*)(ws + oProj);

  const size_t prepN = nW + nW + nWcat + 96;
  prep_kernel<<<dim3((unsigned)((prepN + 255) / 256)), 256, 0, stream>>>(
      Wv, Wo, Woff, Wwt, boff, bwt, Wvt, Wot, Wch, Wcl, bcat);

  // vGEMM (768 blocks, 2-phase dbuf) + proj GEMM (256 blocks, single-buf)
  fat_kernel<<<dim3(256 + 768), 256, 0, stream>>>(
      value, Wvt, bv, vB, query, Wch, Wcl, bcat, proj);

  // fused: coords + softmax + bilinear gather -> LDS agg -> out GEMM
  tail_kernel<<<dim3(512), 512, 0, stream>>>(proj, vB, Wot, bo, out);
}

// Round 7
// 263.599 us; speedup vs baseline: 1.1843x; 1.0051x over previous
//
#include <hip/hip_runtime.h>
#include <hip/hip_bf16.h>
#include <stdint.h>

using bf16 = __hip_bfloat16;

typedef __attribute__((ext_vector_type(8))) short short8;
typedef __attribute__((ext_vector_type(4))) float float4v;

namespace {
constexpr int kL  = 4096;
constexpr int kD  = 384;
constexpr int kGW = 64;
constexpr int kM  = 32768;
constexpr int kAP = 392;   // padded agg LDS stride (bf16): 784 B/row -> 2-way (free) banks

constexpr size_t nValue = (size_t)kM * kD;
constexpr size_t nW     = (size_t)kD * kD;
constexpr size_t nWcat  = (size_t)96 * kD;   // 96x384 (transposed cat weight)

// workspace offsets (bytes)
constexpr size_t oWvt  = 0;                                    // bf16 Wv^T [384][384]
constexpr size_t oWot  = oWvt  + nW * 2;                       // bf16 Wo^T [384][384]
constexpr size_t oWch  = oWot  + nW * 2;                       // bf16 Wcat^T hi [96][384]
constexpr size_t oWcl  = oWch  + nWcat * 2;                    // bf16 Wcat^T lo [96][384]
constexpr size_t oBcat = oWcl  + nWcat * 2;                    // f32 [96]
constexpr size_t oVB   = (oBcat + 96 * 4 + 255) & ~size_t(255);// bf16 v [kM][384]
constexpr size_t oProj = oVB   + nValue * 2;                   // f32 [kM][96]
}

__device__ __forceinline__ void load_lds_16(const void* g, void* l) {
  __builtin_amdgcn_global_load_lds((const __attribute__((address_space(1))) void*)g,
                                   (__attribute__((address_space(3))) void*)l,
                                   16, 0, 0);
}

__device__ __forceinline__ short bf16bits(float f) {
  bf16 h = __float2bfloat16(f);
  return *reinterpret_cast<short*>(&h);
}

__device__ __forceinline__ float bf16raw2f(unsigned short u) {
  union { unsigned int i; float f; } c;
  c.i = ((unsigned int)u) << 16;
  return c.f;
}

__device__ __forceinline__ short8 pack_hi8(const float4& f0, const float4& f1) {
  short8 hx;
  hx[0] = bf16bits(f0.x); hx[1] = bf16bits(f0.y);
  hx[2] = bf16bits(f0.z); hx[3] = bf16bits(f0.w);
  hx[4] = bf16bits(f1.x); hx[5] = bf16bits(f1.y);
  hx[6] = bf16bits(f1.z); hx[7] = bf16bits(f1.w);
  return hx;
}

__device__ __forceinline__ void pack_hilo8(const float4& f0, const float4& f1,
                                           short8& hx, short8& lx) {
  const float fv[8] = {f0.x, f0.y, f0.z, f0.w, f1.x, f1.y, f1.z, f1.w};
  #pragma unroll
  for (int q = 0; q < 8; ++q) {
    const bf16 h = __float2bfloat16(fv[q]);
    hx[q] = *reinterpret_cast<const short*>(&h);
    const bf16 lo = __float2bfloat16(fv[q] - __bfloat162float(h));
    lx[q] = *reinterpret_cast<const short*>(&lo);
  }
}

// -------------------------------------------------------------------------
// prep (weights only): Wv^T, Wo^T as bf16; Wcat^T split into hi/lo bf16 so
// the proj GEMM can run on MFMA with f32-level accuracy (err ~2^-17 rel).
// -------------------------------------------------------------------------
__global__ void prep_kernel(const float* __restrict__ Wv,
                            const float* __restrict__ Wo,
                            const float* __restrict__ Woff,
                            const float* __restrict__ Wwt,
                            const float* __restrict__ boff,
                            const float* __restrict__ bwt,
                            bf16* __restrict__ Wvt, bf16* __restrict__ Wot,
                            bf16* __restrict__ Wch, bf16* __restrict__ Wcl,
                            float* __restrict__ bcat)
{
  size_t i = (size_t)blockIdx.x * 256 + threadIdx.x;
  if (i < nW) {
    const int n = (int)(i / kD), k = (int)(i % kD);
    Wvt[i] = __float2bfloat16(Wv[(size_t)k * kD + n]);
    return;
  }
  i -= nW;
  if (i < nW) {
    const int n = (int)(i / kD), k = (int)(i % kD);
    Wot[i] = __float2bfloat16(Wo[(size_t)k * kD + n]);
    return;
  }
  i -= nW;
  if (i < nWcat) {
    const int n = (int)(i / kD), k = (int)(i % kD);
    const float val = (n < 64) ? Woff[(size_t)k * 64 + n] : Wwt[(size_t)k * 32 + (n - 64)];
    const bf16 h = __float2bfloat16(val);
    Wch[i] = h;
    Wcl[i] = __float2bfloat16(val - __bfloat162float(h));  // exact residual, then rounded
    return;
  }
  i -= nWcat;
  if (i < 96) bcat[i] = (i < 64) ? boff[i] : bwt[i - 64];
}

// -------------------------------------------------------------------------
// v GEMM body: vB[M,384] = value @ Wv + bv, bf16 out.
// 64x128 tile (M halved vs r5 -> grid 1536, 6 blocks/CU resident): the r5
// counters showed latency-bound at grid-capped 4 blocks/CU; TLP is the
// remaining lever. Same proven 2-phase dbuf schedule, one barrier/kt.
// Swizzle ((row>>1)&3) on 64B rows (2-way = free, verified r5 conflicts=0).
// 4 waves, each 32x64 (2x4 16x16 frags). LDS: A 2x4K + B 2x8K = 24 KB.
// -------------------------------------------------------------------------
__device__ __forceinline__
void vgemm_body(char* smem, int bid,
                const float* __restrict__ A, const bf16* __restrict__ Bt,
                const float* __restrict__ bias, bf16* __restrict__ Cout)
{
  bf16* sA = (bf16*)smem;             // [2][64][32] bf16 swz, 4096 B/buf
  char* sBB = smem + 8192;            // [2][128][32] bf16, 8192 B/buf
  const int tid  = threadIdx.x;
  const int lane = tid & 63;
  const int wave = tid >> 6;
  const int bm = bid / 3, bn = bid % 3;
  const int m0 = bm * 64, n0 = bn * 128;
  const int wm = (wave >> 1) * 32, wn = (wave & 1) * 64;
  const int r16 = lane & 15, quad = lane >> 4;

  float4v acc[2][4];
  #pragma unroll
  for (int i = 0; i < 2; ++i)
    #pragma unroll
    for (int j = 0; j < 4; ++j) acc[i][j] = (float4v){0.f, 0.f, 0.f, 0.f};

  // A: 256 16B-chunks (1/thread). B: 512 chunks (2/thread).
  const int rA = tid >> 2, gA = tid & 3;
  const int wA = rA * 32 + (gA ^ ((rA >> 1) & 3)) * 8;      // swizzled A dest (bf16 elems)
  const int e0 = tid, e1 = tid + 256;
  const int rB0 = e0 >> 2, gB0 = e0 & 3;
  const int rB1 = e1 >> 2, gB1 = e1 & 3;
  const int sBc0 = (gB0 ^ ((rB0 >> 1) & 3)) * 8;            // pre-swizzled B src col
  const int sBc1 = (gB1 ^ ((rB1 >> 1) & 3)) * 8;

  float4 f00, f01;
  auto loadA = [&](int k0) {
    const float* s0 = A + (size_t)(m0 + rA) * kD + k0 + gA * 8;
    f00 = *(const float4*)s0; f01 = *(const float4*)(s0 + 4);
  };
  auto writeA = [&](int buf) {
    *(short8*)(sA + buf * 2048 + wA) = pack_hi8(f00, f01);
  };
  auto stageB = [&](int k0, int buf) {
    load_lds_16(Bt + (size_t)(n0 + rB0) * kD + k0 + sBc0, sBB + buf * 8192 + e0 * 16);
    load_lds_16(Bt + (size_t)(n0 + rB1) * kD + k0 + sBc1, sBB + buf * 8192 + e1 * 16);
  };

  loadA(0);
  stageB(0, 0);
  writeA(0);
  __syncthreads();

  for (int kt = 0; kt < 12; ++kt) {
    const int cur = kt & 1, nxt = cur ^ 1;
    if (kt < 11) {
      loadA((kt + 1) * 32);
      stageB((kt + 1) * 32, nxt);
    }
    const bf16* sAc = sA + cur * 2048;
    const bf16* sBc = (const bf16*)(sBB + cur * 8192);
    short8 av[2], bv[4];
    #pragma unroll
    for (int i = 0; i < 2; ++i) {
      const int row = wm + i * 16 + r16;
      av[i] = *(const short8*)(sAc + row * 32 + (quad ^ ((row >> 1) & 3)) * 8);
    }
    #pragma unroll
    for (int j = 0; j < 4; ++j) {
      const int row = wn + j * 16 + r16;
      bv[j] = *(const short8*)(sBc + row * 32 + (quad ^ ((row >> 1) & 3)) * 8);
    }
    #pragma unroll
    for (int i = 0; i < 2; ++i)
      #pragma unroll
      for (int j = 0; j < 4; ++j)
        acc[i][j] = __builtin_amdgcn_mfma_f32_16x16x32_bf16(av[i], bv[j], acc[i][j], 0, 0, 0);
    if (kt < 11) {
      writeA(nxt);
      __syncthreads();
    }
  }

  #pragma unroll
  for (int j = 0; j < 4; ++j) {
    const int col = n0 + wn + j * 16 + r16;
    const float bj = bias[col];
    #pragma unroll
    for (int i = 0; i < 2; ++i) {
      const int mbase = m0 + wm + i * 16 + quad * 4;
      #pragma unroll
      for (int r = 0; r < 4; ++r)
        Cout[(size_t)(mbase + r) * kD + col] = __float2bfloat16(acc[i][j][r] + bj);
    }
  }
}

// -------------------------------------------------------------------------
// proj GEMM body: proj[M,96] = Q @ Wcat + bcat, split-bf16 MFMA
// (acc = Ahi*Bhi + Ahi*Blo + Alo*Bhi, f32-level accuracy).
// 64-row tiles (512 blocks). Single-buf (20 KB fits the shared 24 KB) with
// T14 reg-prefetch: A global loads for kt+1 issue BEFORE kt's MFMA, so the
// HBM latency hides under compute+barrier; only the L2-hot B stays exposed.
// Swizzle ((row>>1)&3) both sides (rule #21).
// -------------------------------------------------------------------------
__device__ __forceinline__
void proj_body(char* smem, int bid,
               const float* __restrict__ Q,
               const bf16* __restrict__ WhT, const bf16* __restrict__ WlT,
               const float* __restrict__ bc, float* __restrict__ proj)
{
  bf16* sAh = (bf16*)smem;             // [64][32] bf16 swz, 4096 B
  bf16* sAl = (bf16*)(smem + 4096);    // 4096 B
  bf16* sBh = (bf16*)(smem + 8192);    // [96][32] bf16 swz, 6144 B
  bf16* sBl = (bf16*)(smem + 14336);   // 6144 B -> total 20480
  const int tid  = threadIdx.x;
  const int lane = tid & 63;
  const int wave = tid >> 6;
  const int m0 = bid * 64;
  const int wm = (wave >> 1) * 32, wn = (wave & 1) * 48;
  const int r16 = lane & 15, quad = lane >> 4;

  float4v acc[2][3];
  #pragma unroll
  for (int i = 0; i < 2; ++i)
    #pragma unroll
    for (int j = 0; j < 3; ++j) acc[i][j] = (float4v){0.f, 0.f, 0.f, 0.f};

  const int rA = tid >> 2, gA = tid & 3;               // 256 A chunks, 1/thread
  const int jwA = (gA ^ ((rA >> 1) & 3));

  float4 f0, f1;
  auto loadA = [&](int k0) {
    const float* src = Q + (size_t)(m0 + rA) * kD + k0 + gA * 8;
    f0 = *(const float4*)src; f1 = *(const float4*)(src + 4);
  };
  auto writeA = [&]() {
    short8 hx, lx;
    pack_hilo8(f0, f1, hx, lx);
    *(short8*)(sAh + rA * 32 + jwA * 8) = hx;
    *(short8*)(sAl + rA * 32 + jwA * 8) = lx;
  };
  auto stageB = [&](int k0) {
    // 768 chunks (hi 384 + lo 384), 3/thread; branch boundary (tid=128)
    // is a wave boundary so each gload_lds dest stays wave-uniform+lane*16.
    int c = tid;                                    // hi chunks 0..255
    int row = c >> 2, j = c & 3, js = j ^ ((row >> 1) & 3);
    load_lds_16(WhT + (size_t)row * kD + k0 + js * 8, (char*)sBh + c * 16);
    if (tid < 128) {
      c = tid + 256;                                // hi chunks 256..383
      row = c >> 2; j = c & 3; js = j ^ ((row >> 1) & 3);
      load_lds_16(WhT + (size_t)row * kD + k0 + js * 8, (char*)sBh + c * 16);
    } else {
      c = tid - 128;                                // lo chunks 0..127
      row = c >> 2; j = c & 3; js = j ^ ((row >> 1) & 3);
      load_lds_16(WlT + (size_t)row * kD + k0 + js * 8, (char*)sBl + c * 16);
    }
    c = tid + 128;                                  // lo chunks 128..383
    row = c >> 2; j = c & 3; js = j ^ ((row >> 1) & 3);
    load_lds_16(WlT + (size_t)row * kD + k0 + js * 8, (char*)sBl + c * 16);
  };

  loadA(0);
  stageB(0);
  writeA();
  __syncthreads();

  for (int kt = 0; kt < 12; ++kt) {
    if (kt < 11) loadA((kt + 1) * 32);   // T14: issue next A before MFMA

    short8 avh[2], avl[2];
    #pragma unroll
    for (int i = 0; i < 2; ++i) {
      const int row = wm + i * 16 + r16;
      const int ch = quad ^ ((row >> 1) & 3);
      avh[i] = *(const short8*)(sAh + row * 32 + ch * 8);
      avl[i] = *(const short8*)(sAl + row * 32 + ch * 8);
    }
    #pragma unroll
    for (int j = 0; j < 3; ++j) {
      const int row = wn + j * 16 + r16;
      const int ch = quad ^ ((row >> 1) & 3);
      const short8 bvh = *(const short8*)(sBh + row * 32 + ch * 8);
      const short8 bvl = *(const short8*)(sBl + row * 32 + ch * 8);
      #pragma unroll
      for (int i = 0; i < 2; ++i) {
        acc[i][j] = __builtin_amdgcn_mfma_f32_16x16x32_bf16(avh[i], bvh, acc[i][j], 0, 0, 0);
        acc[i][j] = __builtin_amdgcn_mfma_f32_16x16x32_bf16(avh[i], bvl, acc[i][j], 0, 0, 0);
        acc[i][j] = __builtin_amdgcn_mfma_f32_16x16x32_bf16(avl[i], bvh, acc[i][j], 0, 0, 0);
      }
    }
    if (kt < 11) {
      __syncthreads();                  // all reads of buf done
      stageB((kt + 1) * 32);
      writeA();
      __syncthreads();                  // buf republished
    }
  }

  #pragma unroll
  for (int j = 0; j < 3; ++j) {
    const int col = wn + j * 16 + r16;
    const float bj = bc[col];
    #pragma unroll
    for (int i = 0; i < 2; ++i) {
      const int mbase = m0 + wm + i * 16 + quad * 4;
      #pragma unroll
      for (int r = 0; r < 4; ++r)
        proj[(size_t)(mbase + r) * 96 + col] = acc[i][j][r] + bj;
    }
  }
}

// -------------------------------------------------------------------------
// Fat kernel: blocks [0,512) proj GEMM (64-row tiles), [512,2048) v GEMM
// (64x128 tiles). smem 24576 -> 6 blocks/CU resident, 8/CU in grid.
// v-segment chunked XCD swizzle (T1): vb=(idx*8+xcd) -> wgid=xcd*192+idx,
// so each bm's 3 bn-blocks land on ONE XCD (shared A rows stay L2-local).
// -------------------------------------------------------------------------
__global__ __launch_bounds__(256)
void fat_kernel(const float* __restrict__ value, const bf16* __restrict__ Wvt,
                const float* __restrict__ bv,    bf16* __restrict__ vB,
                const float* __restrict__ Q,     const bf16* __restrict__ Wch,
                const bf16* __restrict__ Wcl,    const float* __restrict__ bcat,
                float* __restrict__ proj)
{
  __shared__ __align__(16) char smem[24576];
  const int pb = blockIdx.x;
  if (pb < 512) {
    proj_body(smem, pb, Q, Wch, Wcl, bcat, proj);
  } else {
    const int vb   = pb - 512;                 // 0..1535; XCD = vb & 7
    const int wgid = (vb & 7) * 192 + (vb >> 3);
    vgemm_body(smem, wgid, value, Wvt, bv, vB);
  }
}

// -------------------------------------------------------------------------
// tail kernel: fused sample + output GEMM. 512 blocks x 512 thr,
// 64 tokens/block, LDS 66,560 B -> 2 blocks/CU.
//  phase 1 (4 chunks of 16 tokens): coords+softmax -> scratch, then
//    bilinear gather with 16 B (8-dim) scattered loads — HALF the
//    address-divergent instructions of the 4-dim version (the tail's
//    TA-throughput bound) -> sAgg[64][392] bf16.
//  phase 2: out[64][384] = sAgg @ Wo^T + bo. A from LDS, B direct from
//    L2 (Wo^T 288 KB hot; each wave owns a distinct 48-col slice).
// XCD swizzle: chunk = (raw%8)*64 + raw/8 -> each XCD owns one batch's
// v slice (3.1 MB, L2-resident).
// -------------------------------------------------------------------------
__global__ __launch_bounds__(512)
void tail_kernel(const float* __restrict__ proj, const bf16* __restrict__ v,
                 const bf16* __restrict__ Wot, const float* __restrict__ bo,
                 float* __restrict__ out)
{
  __shared__ __align__(16) char smem[66560];
  bf16*   sAgg  = (bf16*)smem;                 // [64][392] = 50176 B
  int4*   scoff = (int4*)(smem + 50176);       // [512] = 8192 B
  float4* scw   = (float4*)(smem + 58368);     // [512] = 8192 B

  const int raw   = blockIdx.x;
  const int chunk = (raw & 7) * 64 + (raw >> 3);
  const int m0    = chunk * 64;
  const int b     = m0 >> 12;
  const int l0    = m0 & 4095;
  const int t     = threadIdx.x;

  // ---------------- phase 1: sample ----------------
  for (int ct = 0; ct < 4; ++ct) {
    const int tok0 = ct * 16;
    {
      const int tl = t >> 5, pt = t & 31;      // 16 tok x 32 pts, 1/thread
      const int tok = tok0 + tl;
      const int l   = l0 + tok;
      const float* pb_ = proj + (size_t)(m0 + tok) * 96;
      const float2 off = *(const float2*)(pb_ + 2 * pt);
      const int h = pt >> 2, p = pt & 3;
      const float4 lg = *(const float4*)(pb_ + 64 + h * 4);
      const float g[4] = {lg.x, lg.y, lg.z, lg.w};
      const float mx = fmaxf(fmaxf(g[0], g[1]), fmaxf(g[2], g[3]));
      float e[4], sum = 0.f;
      #pragma unroll
      for (int jj = 0; jj < 4; ++jj) { e[jj] = expf(g[jj] - mx); sum += e[jj]; }
      const float wt = e[p] / sum;
      const float refx = (float)(l & 63) * (1.0f / 63.0f);
      const float refy = (float)(l >> 6) * (1.0f / 63.0f);
      const float locx = fminf(fmaxf(refx + off.x, 0.f), 1.f);
      const float locy = fminf(fmaxf(refy + off.y, 0.f), 1.f);
      const float ph = locx * 63.0f;           // faithful: component 0 -> row coord
      const float pw = locy * 63.0f;
      const float fy = floorf(ph), fx = floorf(pw);
      const int y0 = (int)fy, x0 = (int)fx;
      const int y1 = min(y0 + 1, 63), x1 = min(x0 + 1, 63);
      const float wy = ph - fy, wx = pw - fx;
      scoff[tl * 32 + pt] = make_int4((y0 * kGW + x0) * kD, (y0 * kGW + x1) * kD,
                                      (y1 * kGW + x0) * kD, (y1 * kGW + x1) * kD);
      scw[tl * 32 + pt] = make_float4(wt * (1.f - wy) * (1.f - wx), wt * (1.f - wy) * wx,
                                      wt * wy * (1.f - wx),         wt * wy * wx);
    }
    __syncthreads();
    // gather: 768 tasks = 16 tok x 48 groups of 8 dims, 16 B loads
    #pragma unroll
    for (int it = 0; it < 2; ++it) {
      const int task = t + it * 512;           // 0..1023, valid < 768
      if (task < 768) {
        const int tl = task / 48;
        const int g  = task - tl * 48;
        const int h  = g / 6;                  // 6 groups per head (48 dims)
        const int col = g * 8;
        const bf16* vb = v + (size_t)b * kL * kD + col;
        float av[8] = {0.f, 0.f, 0.f, 0.f, 0.f, 0.f, 0.f, 0.f};
        #pragma unroll
        for (int p = 0; p < 4; ++p) {
          const int4   o = scoff[tl * 32 + h * 4 + p];
          const float4 w = scw  [tl * 32 + h * 4 + p];
          const short8 u0 = *(const short8*)(vb + o.x);
          const short8 u1 = *(const short8*)(vb + o.y);
          const short8 u2 = *(const short8*)(vb + o.z);
          const short8 u3 = *(const short8*)(vb + o.w);
          #pragma unroll
          for (int d = 0; d < 8; ++d) {
            av[d] += w.x * bf16raw2f((unsigned short)u0[d])
                   + w.y * bf16raw2f((unsigned short)u1[d])
                   + w.z * bf16raw2f((unsigned short)u2[d])
                   + w.w * bf16raw2f((unsigned short)u3[d]);
          }
        }
        short8 ou;
        #pragma unroll
        for (int d = 0; d < 8; ++d) ou[d] = bf16bits(av[d]);
        *(short8*)(sAgg + (size_t)(tok0 + tl) * kAP + col) = ou;
      }
    }
    __syncthreads();   // gather done; scratch reusable / sAgg rows published
  }

  // ---------------- phase 2: out = sAgg @ Wo^T + bo (no barriers) --------
  const int lane = t & 63, wave = t >> 6;
  const int r16 = lane & 15, quad = lane >> 4;
  const int wn = wave * 48;                    // 8 waves x 48 cols = 384
  float4v acc2[4][3];
  #pragma unroll
  for (int i = 0; i < 4; ++i)
    #pragma unroll
    for (int j = 0; j < 3; ++j) acc2[i][j] = (float4v){0.f, 0.f, 0.f, 0.f};

  const bf16* Bbase = Wot + (size_t)(wn + r16) * kD + quad * 8;

  #pragma unroll
  for (int kt = 0; kt < 12; ++kt) {
    const int k0 = kt * 32;
    short8 av[4];
    #pragma unroll
    for (int i = 0; i < 4; ++i)
      av[i] = *(const short8*)(sAgg + (size_t)(i * 16 + r16) * kAP + k0 + quad * 8);
    #pragma unroll
    for (int j = 0; j < 3; ++j) {
      const short8 bvj = *(const short8*)(Bbase + (size_t)(j * 16) * kD + k0);
      #pragma unroll
      for (int i = 0; i < 4; ++i)
        acc2[i][j] = __builtin_amdgcn_mfma_f32_16x16x32_bf16(av[i], bvj, acc2[i][j], 0, 0, 0);
    }
  }

  #pragma unroll
  for (int j = 0; j < 3; ++j) {
    const int col = wn + j * 16 + r16;
    const float bj = bo[col];
    #pragma unroll
    for (int i = 0; i < 4; ++i) {
      const int mb = m0 + i * 16 + quad * 4;
      #pragma unroll
      for (int r = 0; r < 4; ++r)
        out[(size_t)(mb + r) * kD + col] = acc2[i][j][r] + bj;
    }
  }
}

extern "C" void kernel_launch(void* const* d_in, const int* in_sizes, int n_in,
                              void* d_out, int out_size, void* d_ws, size_t ws_size,
                              hipStream_t stream)
{
  const float* query = (const float*)d_in[0];
  const float* value = (const float*)d_in[2];
  const float* Wv    = (const float*)d_in[7];
  const float* bv    = (const float*)d_in[8];
  const float* Woff  = (const float*)d_in[9];
  const float* boff  = (const float*)d_in[10];
  const float* Wwt   = (const float*)d_in[11];
  const float* bwt   = (const float*)d_in[12];
  const float* Wo    = (const float*)d_in[13];
  const float* bo    = (const float*)d_in[14];
  float* out = (float*)d_out;

  char* ws = (char*)d_ws;
  bf16*  Wvt  = (bf16*)(ws + oWvt);
  bf16*  Wot  = (bf16*)(ws + oWot);
  bf16*  Wch  = (bf16*)(ws + oWch);
  bf16*  Wcl  = (bf16*)(ws + oWcl);
  float* bcat = (float*)(ws + oBcat);
  bf16*  vB   = (bf16*)(ws + oVB);
  float* proj = (float*)(ws + oProj);

  const size_t prepN = nW + nW + nWcat + 96;
  prep_kernel<<<dim3((unsigned)((prepN + 255) / 256)), 256, 0, stream>>>(
      Wv, Wo, Woff, Wwt, boff, bwt, Wvt, Wot, Wch, Wcl, bcat);

  // vGEMM (1536 blocks, 64x128 dbuf) + proj GEMM (512 blocks, 64-row T14)
  fat_kernel<<<dim3(512 + 1536), 256, 0, stream>>>(
      value, Wvt, bv, vB, query, Wch, Wcl, bcat, proj);

  // fused: coords + softmax + bilinear gather (16B loads) -> out GEMM
  tail_kernel<<<dim3(512), 512, 0, stream>>>(proj, vB, Wot, bo, out);
}